// Round 3
// baseline (916.939 us; speedup 1.0000x reference)
//
#include <hip/hip_runtime.h>

#define NN 100000   // nodes
#define NE 3200000  // edges
#define NF 512      // in features
#define NH 16       // hidden
#define NC 7        // classes

#define NBUCK 782           // ceil(NN/128); bucket = dst >> 7 (128 nodes/bucket)
#define PBLK 196            // partition blocks
#define EPT 64              // edges per thread in partition kernels (196*256*64 >= NE)

// ---------------------------------------------------------------------------
// Packed butterfly reduction for gemm1 (see R2).
// ---------------------------------------------------------------------------
__device__ __forceinline__ float reduce16(const float acc[16], int lane) {
  float w8[8];
#pragma unroll
  for (int i = 0; i < 8; ++i) {
    float sel = (lane & 1) ? acc[2 * i + 1] : acc[2 * i];
    float oth = (lane & 1) ? acc[2 * i]     : acc[2 * i + 1];
    w8[i] = sel + __shfl_xor(oth, 1);
  }
  float w4[4];
#pragma unroll
  for (int i = 0; i < 4; ++i) {
    float sel = (lane & 2) ? w8[2 * i + 1] : w8[2 * i];
    float oth = (lane & 2) ? w8[2 * i]     : w8[2 * i + 1];
    w4[i] = sel + __shfl_xor(oth, 2);
  }
  float w2[2];
#pragma unroll
  for (int i = 0; i < 2; ++i) {
    float sel = (lane & 4) ? w4[2 * i + 1] : w4[2 * i];
    float oth = (lane & 4) ? w4[2 * i]     : w4[2 * i + 1];
    w2[i] = sel + __shfl_xor(oth, 4);
  }
  float sel = (lane & 8) ? w2[1] : w2[0];
  float oth = (lane & 8) ? w2[0] : w2[1];
  float v = sel + __shfl_xor(oth, 8);
  v += __shfl_xor(v, 16);
  v += __shfl_xor(v, 32);
  return v;
}

// ---------------------------------------------------------------------------
// GEMM1: h0 = x @ W1.  One wave per 2 rows, W1 in 128 VGPRs/lane.
// ---------------------------------------------------------------------------
__global__ __launch_bounds__(256) void gemm1_kernel(const float* __restrict__ x,
                                                    const float* __restrict__ W1,
                                                    float* __restrict__ h0) {
  const int lane = threadIdx.x & 63;
  const int wave = (blockIdx.x * blockDim.x + threadIdx.x) >> 6;
  const int nw   = (gridDim.x * blockDim.x) >> 6;

  float w[8][NH];
#pragma unroll
  for (int i = 0; i < 4; ++i)
#pragma unroll
    for (int j = 0; j < NH; ++j) {
      w[i][j]     = W1[(4 * lane + i) * NH + j];
      w[4 + i][j] = W1[(256 + 4 * lane + i) * NH + j];
    }

  for (int pr = wave; pr < NN / 2; pr += nw) {
    int r0 = 2 * pr;
    const float4* x0 = (const float4*)(x + (size_t)r0 * NF);
    const float4* x1 = (const float4*)(x + (size_t)(r0 + 1) * NF);
    float4 a0 = x0[lane], b0 = x0[64 + lane];
    float4 a1 = x1[lane], b1 = x1[64 + lane];
    float A0[8] = {a0.x, a0.y, a0.z, a0.w, b0.x, b0.y, b0.z, b0.w};
    float A1[8] = {a1.x, a1.y, a1.z, a1.w, b1.x, b1.y, b1.z, b1.w};
    float c0[NH], c1[NH];
#pragma unroll
    for (int j = 0; j < NH; ++j) { c0[j] = 0.f; c1[j] = 0.f; }
#pragma unroll
    for (int i = 0; i < 8; ++i)
#pragma unroll
      for (int j = 0; j < NH; ++j) {
        c0[j] += A0[i] * w[i][j];
        c1[j] += A1[i] * w[i][j];
      }
    float v0 = reduce16(c0, lane);
    float v1 = reduce16(c1, lane);
    if (lane < 16)      h0[(size_t)r0 * NH + lane] = v0;
    else if (lane < 32) h0[(size_t)(r0 + 1) * NH + (lane & 15)] = v1;
  }
}

// ---------------------------------------------------------------------------
// Bucket histogram: per-block LDS hist over 782 buckets, one global atomic
// per (block, nonempty bucket).
// ---------------------------------------------------------------------------
__global__ __launch_bounds__(256) void bucket_hist_kernel(const int* __restrict__ ei,
                                                          int* __restrict__ gcount) {
  __shared__ int hist[NBUCK];
  for (int i = threadIdx.x; i < NBUCK; i += 256) hist[i] = 0;
  __syncthreads();
  int base = blockIdx.x * (256 * EPT);
#pragma unroll 4
  for (int it = 0; it < EPT; ++it) {
    int e = base + it * 256 + threadIdx.x;
    if (e < NE) atomicAdd(&hist[ei[NE + e] >> 7], 1);
  }
  __syncthreads();
  for (int i = threadIdx.x; i < NBUCK; i += 256) {
    int c = hist[i];
    if (c) atomicAdd(&gcount[i], c);
  }
}

// ---------------------------------------------------------------------------
// Exclusive scan of bucket counts (single block, 1024 threads).
// gbase[b] = exclusive prefix; gbase[NBUCK] = NE; gcursor = gbase copy.
// ---------------------------------------------------------------------------
__global__ __launch_bounds__(1024) void bucket_scan_kernel(const int* __restrict__ gcount,
                                                           int* __restrict__ gbase,
                                                           int* __restrict__ gcursor) {
  __shared__ int tmp[1024];
  int tid = threadIdx.x;
  int v = (tid < NBUCK) ? gcount[tid] : 0;
  tmp[tid] = v;
  __syncthreads();
  for (int off = 1; off < 1024; off <<= 1) {
    int t = (tid >= off) ? tmp[tid - off] : 0;
    __syncthreads();
    tmp[tid] += t;
    __syncthreads();
  }
  if (tid < NBUCK) {
    int excl = tmp[tid] - v;
    gbase[tid]   = excl;
    gcursor[tid] = excl;
  }
  if (tid == 0) gbase[NBUCK] = NE;
}

// ---------------------------------------------------------------------------
// Partition (multi-split): edges -> ebuf grouped by bucket.
// Payload packed: (local_dst << 17) | src  (src < 2^17, local_dst < 128).
// Chunked writes: each block reserves contiguous per-bucket chunks, so write
// amplification is ~1.8x instead of 15x.
// ---------------------------------------------------------------------------
__global__ __launch_bounds__(256) void partition_kernel(const int* __restrict__ ei,
                                                        int* __restrict__ gcursor,
                                                        int* __restrict__ ebuf) {
  __shared__ int hist[NBUCK];
  __shared__ int cbase[NBUCK];
  for (int i = threadIdx.x; i < NBUCK; i += 256) hist[i] = 0;
  __syncthreads();
  int base = blockIdx.x * (256 * EPT);
#pragma unroll 4
  for (int it = 0; it < EPT; ++it) {
    int e = base + it * 256 + threadIdx.x;
    if (e < NE) atomicAdd(&hist[ei[NE + e] >> 7], 1);
  }
  __syncthreads();
  for (int i = threadIdx.x; i < NBUCK; i += 256) {
    int c = hist[i];
    cbase[i] = c ? atomicAdd(&gcursor[i], c) : 0;
  }
  __syncthreads();
  for (int i = threadIdx.x; i < NBUCK; i += 256) hist[i] = 0;
  __syncthreads();
#pragma unroll 4
  for (int it = 0; it < EPT; ++it) {
    int e = base + it * 256 + threadIdx.x;
    if (e < NE) {
      int d = ei[NE + e];
      int s = ei[e];
      int b = d >> 7;
      int off = atomicAdd(&hist[b], 1);
      ebuf[cbase[b] + off] = ((d & 127) << 17) | s;
    }
  }
}

// ---------------------------------------------------------------------------
// Layer-1 aggregate + relu + bias + W2, one block per bucket.
// LDS accumulator 128 nodes x 16 feats, row stride 17 (odd -> banks spread).
// 4 lanes per edge (float4 gather of h0 row), ds_add_f32 accumulation.
// Epilogue writes p[node, 0:8] = [relu(acc+b1) @ W2, pad 0], stride 8.
// ---------------------------------------------------------------------------
__global__ __launch_bounds__(256) void agg1_kernel(const int* __restrict__ gbase,
                                                   const int* __restrict__ ebuf,
                                                   const float* __restrict__ h0,
                                                   const float* __restrict__ b1,
                                                   const float* __restrict__ W2,
                                                   float* __restrict__ p) {
  __shared__ float acc[128 * 17];
  for (int i = threadIdx.x; i < 128 * 17; i += 256) acc[i] = 0.f;
  __syncthreads();
  int b = blockIdx.x;
  int start = gbase[b], end = gbase[b + 1];
  int eg = threadIdx.x >> 2, c = threadIdx.x & 3;
  for (int e = start + eg; e < end; e += 64) {
    int pk = ebuf[e];
    int s  = pk & 0x1FFFF;
    int li = pk >> 17;
    float4 hv = *(const float4*)(h0 + (size_t)s * NH + 4 * c);
    float* a = &acc[li * 17 + 4 * c];
    atomicAdd(a + 0, hv.x);
    atomicAdd(a + 1, hv.y);
    atomicAdd(a + 2, hv.z);
    atomicAdd(a + 3, hv.w);
  }
  __syncthreads();
  int li = threadIdx.x;
  if (li < 128) {
    int node = (b << 7) + li;
    if (node < NN) {
      float h[NH];
#pragma unroll
      for (int k = 0; k < NH; ++k) h[k] = fmaxf(acc[li * 17 + k] + b1[k], 0.f);
      float o[8];
#pragma unroll
      for (int j = 0; j < NC; ++j) {
        float s = 0.f;
#pragma unroll
        for (int k = 0; k < NH; ++k) s += h[k] * W2[k * NC + j];
        o[j] = s;
      }
      o[7] = 0.f;
      float4* pr = (float4*)(p + (size_t)node * 8);
      pr[0] = make_float4(o[0], o[1], o[2], o[3]);
      pr[1] = make_float4(o[4], o[5], o[6], o[7]);
    }
  }
}

// ---------------------------------------------------------------------------
// Layer-2 aggregate + bias + log_softmax, one block per bucket.
// LDS accumulator 128 x 8, row stride 9.  2 lanes per edge (float4 of p).
// ---------------------------------------------------------------------------
__global__ __launch_bounds__(256) void agg2_kernel(const int* __restrict__ gbase,
                                                   const int* __restrict__ ebuf,
                                                   const float* __restrict__ p,
                                                   const float* __restrict__ b2,
                                                   float* __restrict__ out) {
  __shared__ float acc[128 * 9];
  for (int i = threadIdx.x; i < 128 * 9; i += 256) acc[i] = 0.f;
  __syncthreads();
  int b = blockIdx.x;
  int start = gbase[b], end = gbase[b + 1];
  int eg = threadIdx.x >> 1, c = threadIdx.x & 1;
  for (int e = start + eg; e < end; e += 128) {
    int pk = ebuf[e];
    int s  = pk & 0x1FFFF;
    int li = pk >> 17;
    float4 pv = *(const float4*)(p + (size_t)s * 8 + 4 * c);
    float* a = &acc[li * 9 + 4 * c];
    atomicAdd(a + 0, pv.x);
    atomicAdd(a + 1, pv.y);
    atomicAdd(a + 2, pv.z);
    atomicAdd(a + 3, pv.w);   // c==1 lane 3 adds the zero pad -> harmless
  }
  __syncthreads();
  int li = threadIdx.x;
  if (li < 128) {
    int node = (b << 7) + li;
    if (node < NN) {
      float z[NC];
      float m = -1e30f;
#pragma unroll
      for (int j = 0; j < NC; ++j) {
        z[j] = acc[li * 9 + j] + b2[j];
        m = fmaxf(m, z[j]);
      }
      float s = 0.f;
#pragma unroll
      for (int j = 0; j < NC; ++j) s += __expf(z[j] - m);
      float l = __logf(s);
#pragma unroll
      for (int j = 0; j < NC; ++j) out[(size_t)node * NC + j] = z[j] - m - l;
    }
  }
}

extern "C" void kernel_launch(void* const* d_in, const int* in_sizes, int n_in,
                              void* d_out, int out_size, void* d_ws, size_t ws_size,
                              hipStream_t stream) {
  const float* x  = (const float*)d_in[0];
  const int*   ei = (const int*)d_in[1];
  const float* W1 = (const float*)d_in[2];
  const float* b1 = (const float*)d_in[3];
  const float* W2 = (const float*)d_in[4];
  const float* b2 = (const float*)d_in[5];
  float* out = (float*)d_out;

  // ws layout (~22.4 MB)
  float* h0      = (float*)d_ws;                    // NN*16
  float* p       = h0 + (size_t)NN * NH;            // NN*8
  int*   ebuf    = (int*)(p + (size_t)NN * 8);      // NE
  int*   gcount  = ebuf + NE;                       // NBUCK
  int*   gbase   = gcount + NBUCK;                  // NBUCK+1
  int*   gcursor = gbase + NBUCK + 1;               // NBUCK

  hipMemsetAsync(gcount, 0, NBUCK * sizeof(int), stream);
  bucket_hist_kernel<<<PBLK, 256, 0, stream>>>(ei, gcount);
  bucket_scan_kernel<<<1, 1024, 0, stream>>>(gcount, gbase, gcursor);
  partition_kernel<<<PBLK, 256, 0, stream>>>(ei, gcursor, ebuf);
  gemm1_kernel<<<2048, 256, 0, stream>>>(x, W1, h0);
  agg1_kernel<<<NBUCK, 256, 0, stream>>>(gbase, ebuf, h0, b1, W2, p);
  agg2_kernel<<<NBUCK, 256, 0, stream>>>(gbase, ebuf, p, b2, out);
}

// Round 4
// 891.286 us; speedup vs baseline: 1.0288x; 1.0288x over previous
//
#include <hip/hip_runtime.h>

#define NN 100000   // nodes
#define NE 3200000  // edges
#define NF 512      // in features
#define NH 16       // hidden
#define NC 7        // classes

#define NBUCK 782   // ceil(NN/128); bucket = dst >> 7 (128 nodes/bucket)
#define PBLK 256    // partition/hist blocks (grid-stride over int4)

// ---------------------------------------------------------------------------
// Packed butterfly reduction: acc[16] -> every lane holds full sum of col
// (lane&15).  17 shuffles.
// ---------------------------------------------------------------------------
__device__ __forceinline__ float reduce16(const float acc[16], int lane) {
  float w8[8];
#pragma unroll
  for (int i = 0; i < 8; ++i) {
    float sel = (lane & 1) ? acc[2 * i + 1] : acc[2 * i];
    float oth = (lane & 1) ? acc[2 * i]     : acc[2 * i + 1];
    w8[i] = sel + __shfl_xor(oth, 1);
  }
  float w4[4];
#pragma unroll
  for (int i = 0; i < 4; ++i) {
    float sel = (lane & 2) ? w8[2 * i + 1] : w8[2 * i];
    float oth = (lane & 2) ? w8[2 * i]     : w8[2 * i + 1];
    w4[i] = sel + __shfl_xor(oth, 2);
  }
  float w2[2];
#pragma unroll
  for (int i = 0; i < 2; ++i) {
    float sel = (lane & 4) ? w4[2 * i + 1] : w4[2 * i];
    float oth = (lane & 4) ? w4[2 * i]     : w4[2 * i + 1];
    w2[i] = sel + __shfl_xor(oth, 4);
  }
  float sel = (lane & 8) ? w2[1] : w2[0];
  float oth = (lane & 8) ? w2[0] : w2[1];
  float v = sel + __shfl_xor(oth, 8);
  v += __shfl_xor(v, 16);
  v += __shfl_xor(v, 32);
  return v;
}

// ---------------------------------------------------------------------------
// GEMM1: h0 = x @ W1.  One wave per 2 rows, W1 in 128 VGPRs/lane.
// ---------------------------------------------------------------------------
__global__ __launch_bounds__(256) void gemm1_kernel(const float* __restrict__ x,
                                                    const float* __restrict__ W1,
                                                    float* __restrict__ h0) {
  const int lane = threadIdx.x & 63;
  const int wave = (blockIdx.x * blockDim.x + threadIdx.x) >> 6;
  const int nw   = (gridDim.x * blockDim.x) >> 6;

  float w[8][NH];
#pragma unroll
  for (int i = 0; i < 4; ++i)
#pragma unroll
    for (int j = 0; j < NH; ++j) {
      w[i][j]     = W1[(4 * lane + i) * NH + j];
      w[4 + i][j] = W1[(256 + 4 * lane + i) * NH + j];
    }

  for (int pr = wave; pr < NN / 2; pr += nw) {
    int r0 = 2 * pr;
    const float4* x0 = (const float4*)(x + (size_t)r0 * NF);
    const float4* x1 = (const float4*)(x + (size_t)(r0 + 1) * NF);
    float4 a0 = x0[lane], b0 = x0[64 + lane];
    float4 a1 = x1[lane], b1 = x1[64 + lane];
    float A0[8] = {a0.x, a0.y, a0.z, a0.w, b0.x, b0.y, b0.z, b0.w};
    float A1[8] = {a1.x, a1.y, a1.z, a1.w, b1.x, b1.y, b1.z, b1.w};
    float c0[NH], c1[NH];
#pragma unroll
    for (int j = 0; j < NH; ++j) { c0[j] = 0.f; c1[j] = 0.f; }
#pragma unroll
    for (int i = 0; i < 8; ++i)
#pragma unroll
      for (int j = 0; j < NH; ++j) {
        c0[j] += A0[i] * w[i][j];
        c1[j] += A1[i] * w[i][j];
      }
    float v0 = reduce16(c0, lane);
    float v1 = reduce16(c1, lane);
    if (lane < 16)      h0[(size_t)r0 * NH + lane] = v0;
    else if (lane < 32) h0[(size_t)(r0 + 1) * NH + (lane & 15)] = v1;
  }
}

// ---------------------------------------------------------------------------
// Bucket histogram, int4-vectorized grid-stride.
// ---------------------------------------------------------------------------
__global__ __launch_bounds__(256) void bucket_hist_kernel(const int* __restrict__ ei,
                                                          int* __restrict__ gcount) {
  __shared__ int hist[NBUCK];
  for (int i = threadIdx.x; i < NBUCK; i += 256) hist[i] = 0;
  __syncthreads();
  const int4* d4 = (const int4*)(ei + NE);
  int stride = gridDim.x * 256;
  for (int i = blockIdx.x * 256 + threadIdx.x; i < NE / 4; i += stride) {
    int4 v = d4[i];
    atomicAdd(&hist[v.x >> 7], 1);
    atomicAdd(&hist[v.y >> 7], 1);
    atomicAdd(&hist[v.z >> 7], 1);
    atomicAdd(&hist[v.w >> 7], 1);
  }
  __syncthreads();
  for (int i = threadIdx.x; i < NBUCK; i += 256) {
    int c = hist[i];
    if (c) atomicAdd(&gcount[i], c);
  }
}

// ---------------------------------------------------------------------------
// Exclusive scan of bucket counts.
// ---------------------------------------------------------------------------
__global__ __launch_bounds__(1024) void bucket_scan_kernel(const int* __restrict__ gcount,
                                                           int* __restrict__ gbase,
                                                           int* __restrict__ gcursor) {
  __shared__ int tmp[1024];
  int tid = threadIdx.x;
  int v = (tid < NBUCK) ? gcount[tid] : 0;
  tmp[tid] = v;
  __syncthreads();
  for (int off = 1; off < 1024; off <<= 1) {
    int t = (tid >= off) ? tmp[tid - off] : 0;
    __syncthreads();
    tmp[tid] += t;
    __syncthreads();
  }
  if (tid < NBUCK) {
    int excl = tmp[tid] - v;
    gbase[tid]   = excl;
    gcursor[tid] = excl;
  }
  if (tid == 0) gbase[NBUCK] = NE;
}

// ---------------------------------------------------------------------------
// Partition: chunked multi-split, int4-vectorized, identical traversal in
// both phases.  Payload: (local_dst << 17) | src.
// ---------------------------------------------------------------------------
__global__ __launch_bounds__(256) void partition_kernel(const int* __restrict__ ei,
                                                        int* __restrict__ gcursor,
                                                        int* __restrict__ ebuf) {
  __shared__ int hist[NBUCK];
  __shared__ int cbase[NBUCK];
  for (int i = threadIdx.x; i < NBUCK; i += 256) hist[i] = 0;
  __syncthreads();
  const int4* d4 = (const int4*)(ei + NE);
  const int4* s4 = (const int4*)ei;
  int stride = gridDim.x * 256;
  for (int i = blockIdx.x * 256 + threadIdx.x; i < NE / 4; i += stride) {
    int4 v = d4[i];
    atomicAdd(&hist[v.x >> 7], 1);
    atomicAdd(&hist[v.y >> 7], 1);
    atomicAdd(&hist[v.z >> 7], 1);
    atomicAdd(&hist[v.w >> 7], 1);
  }
  __syncthreads();
  for (int i = threadIdx.x; i < NBUCK; i += 256) {
    int c = hist[i];
    cbase[i] = c ? atomicAdd(&gcursor[i], c) : 0;
  }
  __syncthreads();
  for (int i = threadIdx.x; i < NBUCK; i += 256) hist[i] = 0;
  __syncthreads();
  for (int i = blockIdx.x * 256 + threadIdx.x; i < NE / 4; i += stride) {
    int4 d = d4[i];
    int4 s = s4[i];
    int b0 = d.x >> 7, b1 = d.y >> 7, b2 = d.z >> 7, b3 = d.w >> 7;
    int o0 = atomicAdd(&hist[b0], 1);
    int o1 = atomicAdd(&hist[b1], 1);
    int o2 = atomicAdd(&hist[b2], 1);
    int o3 = atomicAdd(&hist[b3], 1);
    ebuf[cbase[b0] + o0] = ((d.x & 127) << 17) | s.x;
    ebuf[cbase[b1] + o1] = ((d.y & 127) << 17) | s.y;
    ebuf[cbase[b2] + o2] = ((d.z & 127) << 17) | s.z;
    ebuf[cbase[b3] + o3] = ((d.w & 127) << 17) | s.w;
  }
}

// ---------------------------------------------------------------------------
// Layer-1 aggregate + relu + bias + W2.  One block per bucket; 4 lanes/edge;
// unroll 8 with batched independent loads (8 gathers in flight per thread).
// LDS acc 128 x 16, row stride 17.
// ---------------------------------------------------------------------------
__global__ __launch_bounds__(256) void agg1_kernel(const int* __restrict__ gbase,
                                                   const int* __restrict__ ebuf,
                                                   const float* __restrict__ h0,
                                                   const float* __restrict__ b1,
                                                   const float* __restrict__ W2,
                                                   float* __restrict__ p) {
  __shared__ float acc[128 * 17];
  for (int i = threadIdx.x; i < 128 * 17; i += 256) acc[i] = 0.f;
  __syncthreads();
  int b = blockIdx.x;
  int start = gbase[b], end = gbase[b + 1];
  int eg = threadIdx.x >> 2, c = threadIdx.x & 3;
  int nIter = (end - start + 511) >> 9;   // 512 edges per block-iter
  int e = start + eg;
  for (int it = 0; it < nIter; ++it, e += 512) {
    int pk[8];
#pragma unroll
    for (int u = 0; u < 8; ++u) {
      int ee = e + (u << 6);
      pk[u] = ebuf[ee < end ? ee : start];
    }
    float4 hv[8];
#pragma unroll
    for (int u = 0; u < 8; ++u) {
      int s = pk[u] & 0x1FFFF;
      hv[u] = *(const float4*)(h0 + (size_t)s * NH + 4 * c);
    }
#pragma unroll
    for (int u = 0; u < 8; ++u) {
      if (e + (u << 6) < end) {
        int li = pk[u] >> 17;
        float* a = &acc[li * 17 + 4 * c];
        atomicAdd(a + 0, hv[u].x);
        atomicAdd(a + 1, hv[u].y);
        atomicAdd(a + 2, hv[u].z);
        atomicAdd(a + 3, hv[u].w);
      }
    }
  }
  __syncthreads();
  int li = threadIdx.x;
  if (li < 128) {
    int node = (b << 7) + li;
    if (node < NN) {
      float h[NH];
#pragma unroll
      for (int k = 0; k < NH; ++k) h[k] = fmaxf(acc[li * 17 + k] + b1[k], 0.f);
      float o[8];
#pragma unroll
      for (int j = 0; j < NC; ++j) {
        float s = 0.f;
#pragma unroll
        for (int k = 0; k < NH; ++k) s += h[k] * W2[k * NC + j];
        o[j] = s;
      }
      o[7] = 0.f;
      float4* pr = (float4*)(p + (size_t)node * 8);
      pr[0] = make_float4(o[0], o[1], o[2], o[3]);
      pr[1] = make_float4(o[4], o[5], o[6], o[7]);
    }
  }
}

// ---------------------------------------------------------------------------
// Layer-2 aggregate + bias + log_softmax.  2 lanes/edge; unroll 8.
// LDS acc 128 x 8, row stride 9.
// ---------------------------------------------------------------------------
__global__ __launch_bounds__(256) void agg2_kernel(const int* __restrict__ gbase,
                                                   const int* __restrict__ ebuf,
                                                   const float* __restrict__ p,
                                                   const float* __restrict__ b2,
                                                   float* __restrict__ out) {
  __shared__ float acc[128 * 9];
  for (int i = threadIdx.x; i < 128 * 9; i += 256) acc[i] = 0.f;
  __syncthreads();
  int b = blockIdx.x;
  int start = gbase[b], end = gbase[b + 1];
  int eg = threadIdx.x >> 1, c = threadIdx.x & 1;
  int nIter = (end - start + 1023) >> 10;  // 1024 edges per block-iter
  int e = start + eg;
  for (int it = 0; it < nIter; ++it, e += 1024) {
    int pk[8];
#pragma unroll
    for (int u = 0; u < 8; ++u) {
      int ee = e + (u << 7);
      pk[u] = ebuf[ee < end ? ee : start];
    }
    float4 pv[8];
#pragma unroll
    for (int u = 0; u < 8; ++u) {
      int s = pk[u] & 0x1FFFF;
      pv[u] = *(const float4*)(p + (size_t)s * 8 + 4 * c);
    }
#pragma unroll
    for (int u = 0; u < 8; ++u) {
      if (e + (u << 7) < end) {
        int li = pk[u] >> 17;
        float* a = &acc[li * 9 + 4 * c];
        atomicAdd(a + 0, pv[u].x);
        atomicAdd(a + 1, pv[u].y);
        atomicAdd(a + 2, pv[u].z);
        atomicAdd(a + 3, pv[u].w);   // pad lane adds 0 -> harmless
      }
    }
  }
  __syncthreads();
  int li = threadIdx.x;
  if (li < 128) {
    int node = (b << 7) + li;
    if (node < NN) {
      float z[NC];
      float m = -1e30f;
#pragma unroll
      for (int j = 0; j < NC; ++j) {
        z[j] = acc[li * 9 + j] + b2[j];
        m = fmaxf(m, z[j]);
      }
      float s = 0.f;
#pragma unroll
      for (int j = 0; j < NC; ++j) s += __expf(z[j] - m);
      float l = __logf(s);
#pragma unroll
      for (int j = 0; j < NC; ++j) out[(size_t)node * NC + j] = z[j] - m - l;
    }
  }
}

extern "C" void kernel_launch(void* const* d_in, const int* in_sizes, int n_in,
                              void* d_out, int out_size, void* d_ws, size_t ws_size,
                              hipStream_t stream) {
  const float* x  = (const float*)d_in[0];
  const int*   ei = (const int*)d_in[1];
  const float* W1 = (const float*)d_in[2];
  const float* b1 = (const float*)d_in[3];
  const float* W2 = (const float*)d_in[4];
  const float* b2 = (const float*)d_in[5];
  float* out = (float*)d_out;

  float* h0      = (float*)d_ws;                    // NN*16
  float* p       = h0 + (size_t)NN * NH;            // NN*8
  int*   ebuf    = (int*)(p + (size_t)NN * 8);      // NE
  int*   gcount  = ebuf + NE;                       // NBUCK
  int*   gbase   = gcount + NBUCK;                  // NBUCK+1
  int*   gcursor = gbase + NBUCK + 1;               // NBUCK

  hipMemsetAsync(gcount, 0, NBUCK * sizeof(int), stream);
  bucket_hist_kernel<<<PBLK, 256, 0, stream>>>(ei, gcount);
  bucket_scan_kernel<<<1, 1024, 0, stream>>>(gcount, gbase, gcursor);
  partition_kernel<<<PBLK, 256, 0, stream>>>(ei, gcursor, ebuf);
  gemm1_kernel<<<2048, 256, 0, stream>>>(x, W1, h0);
  agg1_kernel<<<NBUCK, 256, 0, stream>>>(gbase, ebuf, h0, b1, W2, p);
  agg2_kernel<<<NBUCK, 256, 0, stream>>>(gbase, ebuf, p, b2, out);
}